// Round 1
// 869.920 us; speedup vs baseline: 1.3535x; 1.3535x over previous
//
#include <hip/hip_runtime.h>
#include <math.h>

// Problem constants (from reference)
constexpr int NN = 50000;   // nodes
constexpr int NE = 800000;  // edges
constexpr int DD = 64;      // feature dim

// ---- monotone float<->uint map for atomicMax on signed floats ----
__device__ __forceinline__ unsigned fmap(float x) {
    unsigned u = __float_as_uint(x);
    return (u & 0x80000000u) ? ~u : (u | 0x80000000u);
}
__device__ __forceinline__ float funmap(unsigned u) {
    unsigned b = (u & 0x80000000u) ? (u & 0x7FFFFFFFu) : ~u;
    return __uint_as_float(b);
}

// wave-uniform broadcast of lane k via v_readlane (SGPR), no LDS traffic
__device__ __forceinline__ float bcast(float x, int k) {
    return __int_as_float(__builtin_amdgcn_readlane(__float_as_int(x), k));
}

// ---- kernel 1: init segment max/sum ----
__global__ void k_init(unsigned* __restrict__ segMax, float* __restrict__ segSum) {
    int i = blockIdx.x * blockDim.x + threadIdx.x;
    if (i < NN) { segMax[i] = 0u; segSum[i] = 0.0f; }
}

// ---- kernel 2: node projections ----
// 4 matrix-passes: wave (wid&3) owns matrix m; its W-column (64 floats) lives in
// VGPRs, x_k broadcast via readlane -> inner loop is 1 readlane + 1 FMA, zero LDS.
__global__ __launch_bounds__(256) void k_node(
    const float* __restrict__ nodes,
    const float* __restrict__ Wsent, const float* __restrict__ bsent,
    const float* __restrict__ Wrecv, const float* __restrict__ brecv,
    const float* __restrict__ Wmsg,  const float* __restrict__ bmsg,
    const float* __restrict__ Wself, const float* __restrict__ bself,
    float* __restrict__ sentP, float* __restrict__ recvP,
    float* __restrict__ msgP,  float* __restrict__ selfOut) {
    const int lane = threadIdx.x & 63;
    const int wid  = (blockIdx.x * 256 + threadIdx.x) >> 6;
    const int nw   = (gridDim.x * 256) >> 6;
    const int m    = wid & 3;
    const int w4   = wid >> 2;
    const int nw4  = nw >> 2;

    const float* W; const float* bias; float* out;
    if (m == 0)      { W = Wsent; bias = bsent; out = sentP; }
    else if (m == 1) { W = Wrecv; bias = brecv; out = recvP; }
    else if (m == 2) { W = Wmsg;  bias = bmsg;  out = msgP; }
    else             { W = Wself; bias = bself; out = selfOut; }

    float Wc[DD];   // column `lane` of W, in registers
    #pragma unroll
    for (int k = 0; k < DD; ++k) Wc[k] = W[k * DD + lane];
    const float b = bias[lane];

    for (int i = w4; i < NN; i += nw4) {
        float x = nodes[i * DD + lane];
        float a0 = b, a1 = 0.0f;   // 2 chains to hide FMA latency
        #pragma unroll
        for (int k = 0; k < DD; k += 2) {
            a0 += bcast(x, k)     * Wc[k];
            a1 += bcast(x, k + 1) * Wc[k + 1];
        }
        out[i * DD + lane] = a0 + a1;
    }
}

// ---- kernel 3: edge features + attention logits + segment max ----
// W_edge column in VGPRs, readlane broadcast: inner loop has ZERO LDS ops.
__global__ __launch_bounds__(256) void k_edge(
    const float* __restrict__ edges,
    const int* __restrict__ senders, const int* __restrict__ receivers,
    const float* __restrict__ Wedge, const float* __restrict__ bedge,
    const float* __restrict__ Wattn, const float* __restrict__ battn,
    const float* __restrict__ sentP, const float* __restrict__ recvP,
    float* __restrict__ edgeOut, float* __restrict__ logits,
    unsigned* __restrict__ segMax) {
    const int lane = threadIdx.x & 63;
    const int wid  = (blockIdx.x * 256 + threadIdx.x) >> 6;
    const int nw   = (gridDim.x * 256) >> 6;

    float Wc[DD];   // column `lane` of W_edge, in registers
    #pragma unroll
    for (int k = 0; k < DD; ++k) Wc[k] = Wedge[k * DD + lane];
    const float be = bedge[lane];
    const float wa = Wattn[lane];
    const float ba = battn[0];

    for (int e = wid; e < NE; e += nw) {
        float x = edges[(size_t)e * DD + lane];
        int s = senders[e], r = receivers[e];
        float g0 = sentP[s * DD + lane];   // issue random gathers early
        float g1 = recvP[r * DD + lane];
        float a0 = be, a1 = 0.0f, a2 = 0.0f, a3 = 0.0f;
        #pragma unroll
        for (int k = 0; k < DD; k += 4) {
            a0 += bcast(x, k)     * Wc[k];
            a1 += bcast(x, k + 1) * Wc[k + 1];
            a2 += bcast(x, k + 2) * Wc[k + 2];
            a3 += bcast(x, k + 3) * Wc[k + 3];
        }
        float ef = (a0 + a1) + (a2 + a3) + g0 + g1;
        edgeOut[(size_t)e * DD + lane] = ef;
        // attention logit: dot(ef, Wattn) + b, leaky_relu(0.01)
        float t = ef * wa;
        #pragma unroll
        for (int off = 32; off > 0; off >>= 1) t += __shfl_down(t, off, 64);
        if (lane == 0) {
            float v = t + ba;
            v = v > 0.0f ? v : 0.01f * v;
            logits[e] = v;
            atomicMax(segMax + r, fmap(v));
        }
    }
}

// ---- kernel 4: exp(logit - segmax), accumulate segment sums ----
__global__ void k_exp(const float* __restrict__ logits,
                      const int* __restrict__ receivers,
                      const unsigned* __restrict__ segMax,
                      float* __restrict__ expv, float* __restrict__ segSum) {
    int e = blockIdx.x * blockDim.x + threadIdx.x;
    if (e < NE) {
        int r = receivers[e];
        float m = funmap(segMax[r]);
        float ex = expf(logits[e] - m);
        expv[e] = ex;
        atomicAdd(segSum + r, ex);
    }
}

// ---- kernel 5: weighted message scatter into new_nodes ----
__global__ __launch_bounds__(256) void k_scatter(
    const int* __restrict__ senders, const int* __restrict__ receivers,
    const float* __restrict__ expv, const float* __restrict__ segSum,
    const float* __restrict__ msgP, float* __restrict__ outNodes) {
    const int lane = threadIdx.x & 63;
    const int wid  = (blockIdx.x * 256 + threadIdx.x) >> 6;
    const int nw   = (gridDim.x * 256) >> 6;
    for (int e = wid; e < NE; e += nw) {
        int s = senders[e], r = receivers[e];
        float w = expv[e] / segSum[r];
        atomicAdd(outNodes + r * DD + lane, w * msgP[s * DD + lane]);
    }
}

extern "C" void kernel_launch(void* const* d_in, const int* in_sizes, int n_in,
                              void* d_out, int out_size, void* d_ws, size_t ws_size,
                              hipStream_t stream) {
    const float* nodes     = (const float*)d_in[0];
    const float* edges     = (const float*)d_in[1];
    const int*   senders   = (const int*)d_in[2];
    const int*   receivers = (const int*)d_in[3];
    const float* Wsent = (const float*)d_in[4];
    const float* bsent = (const float*)d_in[5];
    const float* Wrecv = (const float*)d_in[6];
    const float* brecv = (const float*)d_in[7];
    const float* Wedge = (const float*)d_in[8];
    const float* bedge = (const float*)d_in[9];
    const float* Wattn = (const float*)d_in[10];
    const float* battn = (const float*)d_in[11];
    const float* Wmsg  = (const float*)d_in[12];
    const float* bmsg  = (const float*)d_in[13];
    const float* Wself = (const float*)d_in[14];
    const float* bself = (const float*)d_in[15];

    float* out = (float*)d_out;
    float* outNodes = out;                    // [NN, DD]
    float* outEdge  = out + (size_t)NN * DD;  // [NE, DD]

    // workspace layout
    float* ws = (float*)d_ws;
    float* sentP  = ws;                       // NN*DD
    float* recvP  = sentP + (size_t)NN * DD;  // NN*DD
    float* msgP   = recvP + (size_t)NN * DD;  // NN*DD
    float* logits = msgP  + (size_t)NN * DD;  // NE
    float* expv   = logits + NE;              // NE
    float* segSum = expv + NE;                // NN
    unsigned* segMax = (unsigned*)(segSum + NN); // NN

    k_init<<<(NN + 255) / 256, 256, 0, stream>>>(segMax, segSum);
    k_node<<<512, 256, 0, stream>>>(nodes, Wsent, bsent, Wrecv, brecv,
                                    Wmsg, bmsg, Wself, bself,
                                    sentP, recvP, msgP, outNodes);
    k_edge<<<4096, 256, 0, stream>>>(edges, senders, receivers, Wedge, bedge,
                                     Wattn, battn, sentP, recvP,
                                     outEdge, logits, segMax);
    k_exp<<<(NE + 255) / 256, 256, 0, stream>>>(logits, receivers, segMax, expv, segSum);
    k_scatter<<<4096, 256, 0, stream>>>(senders, receivers, expv, segSum, msgP, outNodes);
}